// Round 1
// 364.165 us; speedup vs baseline: 1.0545x; 1.0545x over previous
//
#include <hip/hip_runtime.h>

// Problem constants
#define R_ 8
#define K_ 32
#define B_ 1024
#define D_ 256
#define L_ 16
#define BCHUNK 128   // b-rows per block in K1

// g_accum layout (floats, in ws after loss_ws):
//   [0,256)   cnt[r*32+k]
//   [256,512) val[r*32+k]
//   [512,520) obj[r]
//   [520]     (int) arrival counter
#define GA_CNT 0
#define GA_VAL 256
#define GA_OBJ 512
#define GA_CTR 520

// native vector type for nontemporal stores (HIP float4 is a class and
// __builtin_nontemporal_store rejects it)
typedef float nfloat4 __attribute__((ext_vector_type(4)));

__device__ __forceinline__ float2 f2fma(float s, float2 u, float2 a) {
    a.x = fmaf(s, u.x, a.x);
    a.y = fmaf(s, u.y, a.y);
    return a;
}

// ---------------------------------------------------------------------------
// K1: fused x_ = z @ Us^T (per r,k) + loss[rk,b] = 0.5*sum_D (x - x_)^2
// grid: R*K*8 = 2048 blocks, 256 threads. Each lane owns 4 consecutive D
// columns (Us rows in 64 VGPRs as float2 pairs -> v_pk_fma_f32). Each wave
// does 32 b-rows, 2 at a time (hoisted loads, 2 independent shfl chains).
// loss_ws layout is now [rk][b]: after the xor-butterfly every lane holds
// the full row sum, so row b0+i's loss is collected into lane i (cndmask)
// and the wave emits ONE coalesced 128B store at the end -- no scattered
// 4B stores, no per-iteration lane0 divergence, no write-allocate RMW.
// Block 0 additionally zero-inits the global accumulators for K2.
// ---------------------------------------------------------------------------
__global__ __launch_bounds__(256) void k1_gemm_loss(
    const float* __restrict__ x, const float* __restrict__ z,
    const float* __restrict__ Us, float* __restrict__ x_out,
    float* __restrict__ loss_ws, float* __restrict__ g_accum)
{
    if (blockIdx.x == 0) {
        const int t = threadIdx.x;
        g_accum[GA_CNT + t] = 0.f;
        g_accum[GA_VAL + t] = 0.f;
        if (t < R_) g_accum[GA_OBJ + t] = 0.f;
        if (t == 0) ((int*)g_accum)[GA_CTR] = 0;
    }

    const int blk   = blockIdx.x;
    const int rk    = blk >> 3;
    const int chunk = blk & 7;
    const int lane = threadIdx.x & 63;
    const int wave = threadIdx.x >> 6;

    const float* Us_rk = Us + (size_t)rk * (D_ * L_);
    const float* z_rk  = z  + (size_t)rk * (B_ * L_);
    float*       xo_rk = x_out + (size_t)rk * (B_ * D_);

    // Pack Us rows for this lane's 4 D columns into float2 pairs:
    // u01[j] = (Us[d0][j], Us[d0+1][j]),  u23[j] = (Us[d0+2][j], Us[d0+3][j])
    const int d0 = lane << 2;
    float2 u01[16], u23[16];
    {
        const float4* r0 = (const float4*)(Us_rk + (size_t)(d0 + 0) * L_);
        const float4* r1 = (const float4*)(Us_rk + (size_t)(d0 + 1) * L_);
        const float4* r2 = (const float4*)(Us_rk + (size_t)(d0 + 2) * L_);
        const float4* r3 = (const float4*)(Us_rk + (size_t)(d0 + 3) * L_);
#pragma unroll
        for (int j4 = 0; j4 < 4; ++j4) {
            float4 a = r0[j4], b = r1[j4], c = r2[j4], d = r3[j4];
            u01[j4 * 4 + 0] = make_float2(a.x, b.x);
            u01[j4 * 4 + 1] = make_float2(a.y, b.y);
            u01[j4 * 4 + 2] = make_float2(a.z, b.z);
            u01[j4 * 4 + 3] = make_float2(a.w, b.w);
            u23[j4 * 4 + 0] = make_float2(c.x, d.x);
            u23[j4 * 4 + 1] = make_float2(c.y, d.y);
            u23[j4 * 4 + 2] = make_float2(c.z, d.z);
            u23[j4 * 4 + 3] = make_float2(c.w, d.w);
        }
    }

    const int b0 = chunk * BCHUNK + wave * (BCHUNK / 4);   // 32 rows per wave
    float loss_acc = 0.f;                                  // lane i <- loss(b0+i)
    for (int i = 0; i < BCHUNK / 4; i += 2) {
        const int ba = b0 + i;
        const int bb = b0 + i + 1;

        // ---- hoist ALL loads for both rows (max MLP) ----
        const float4* zra = (const float4*)(z_rk + (size_t)ba * L_);
        const float4* zrb = (const float4*)(z_rk + (size_t)bb * L_);
        float4 zA[4], zB[4];
#pragma unroll
        for (int j4 = 0; j4 < 4; ++j4) { zA[j4] = zra[j4]; zB[j4] = zrb[j4]; }
        float4 xa = ((const float4*)(x + (size_t)ba * D_))[lane];
        float4 xb = ((const float4*)(x + (size_t)bb * D_))[lane];

        // ---- packed-fp32 dot products ----
        float2 a01 = make_float2(0.f, 0.f), a23 = make_float2(0.f, 0.f);
        float2 b01 = make_float2(0.f, 0.f), b23 = make_float2(0.f, 0.f);
#pragma unroll
        for (int j4 = 0; j4 < 4; ++j4) {
            float4 za = zA[j4], zb = zB[j4];
            a01 = f2fma(za.x, u01[4 * j4 + 0], a01); a23 = f2fma(za.x, u23[4 * j4 + 0], a23);
            a01 = f2fma(za.y, u01[4 * j4 + 1], a01); a23 = f2fma(za.y, u23[4 * j4 + 1], a23);
            a01 = f2fma(za.z, u01[4 * j4 + 2], a01); a23 = f2fma(za.z, u23[4 * j4 + 2], a23);
            a01 = f2fma(za.w, u01[4 * j4 + 3], a01); a23 = f2fma(za.w, u23[4 * j4 + 3], a23);
            b01 = f2fma(zb.x, u01[4 * j4 + 0], b01); b23 = f2fma(zb.x, u23[4 * j4 + 0], b23);
            b01 = f2fma(zb.y, u01[4 * j4 + 1], b01); b23 = f2fma(zb.y, u23[4 * j4 + 1], b23);
            b01 = f2fma(zb.z, u01[4 * j4 + 2], b01); b23 = f2fma(zb.z, u23[4 * j4 + 2], b23);
            b01 = f2fma(zb.w, u01[4 * j4 + 3], b01); b23 = f2fma(zb.w, u23[4 * j4 + 3], b23);
        }

        // ---- streaming nontemporal stores of x_ (never re-read) ----
        nfloat4 oA = { a01.x, a01.y, a23.x, a23.y };
        nfloat4 oB = { b01.x, b01.y, b23.x, b23.y };
        __builtin_nontemporal_store(oA, (nfloat4*)(xo_rk + (size_t)ba * D_) + lane);
        __builtin_nontemporal_store(oB, (nfloat4*)(xo_rk + (size_t)bb * D_) + lane);

        // ---- fused loss: two independent 6-step shfl chains ----
        float dax = xa.x - oA.x, day = xa.y - oA.y, daz = xa.z - oA.z, daw = xa.w - oA.w;
        float dbx = xb.x - oB.x, dby = xb.y - oB.y, dbz = xb.z - oB.z, dbw = xb.w - oB.w;
        float sqA = fmaf(dax, dax, fmaf(day, day, fmaf(daz, daz, daw * daw)));
        float sqB = fmaf(dbx, dbx, fmaf(dby, dby, fmaf(dbz, dbz, dbw * dbw)));
#pragma unroll
        for (int s = 32; s >= 1; s >>= 1) {
            sqA += __shfl_xor(sqA, s, 64);
            sqB += __shfl_xor(sqB, s, 64);
        }
        // full sum lives in every lane after the butterfly; park row ba's
        // loss in lane i and row bb's in lane i+1 (two cndmasks, no branch)
        loss_acc = (lane == i)     ? 0.5f * sqA : loss_acc;
        loss_acc = (lane == i + 1) ? 0.5f * sqB : loss_acc;
    }

    // one coalesced 128B store per wave: loss_ws[rk][b0 + lane]
    if (lane < 32)
        loss_ws[(size_t)rk * B_ + b0 + lane] = loss_acc;
}

// ---------------------------------------------------------------------------
// K2 (rewritten): per-lane serial top-2 scan, zero shuffles.
// grid = 32 blocks x 256 threads; thread t owns cell = blk*256+t = r*B + b
// (r is uniform per block since 256 | 1024). It hoists the 32 losses
// loss_ws[(r*K+k)*B + b] (coalesced 256B/wave per k, L2-resident ~1MB),
// scans min/min2/argmin in registers (lowest index wins ties, matching
// jax.lax.top_k; duplicated min => m2 == m1, same as before), writes the
// one-hot c row as 8 nontemporal float4s, then LDS-atomic histogram ->
// global float atomics -> arrival counter -> last block does the EMA/obj
// epilogue (identical to previous version).
// ---------------------------------------------------------------------------
__global__ __launch_bounds__(256) void k2_top2_final(
    const float* __restrict__ loss_ws, const float* __restrict__ c_mean,
    const float* __restrict__ value, float* __restrict__ c_out,
    float* __restrict__ obj_out, float* __restrict__ obj_mean_out,
    float* __restrict__ ncm_out, float* __restrict__ nv_out,
    float* __restrict__ g_accum, int nblocks)
{
    __shared__ float s_cnt[K_];
    __shared__ float s_val[K_];
    __shared__ float s_obj;
    __shared__ int   s_last;

    const int t    = threadIdx.x;
    const int cell = blockIdx.x * 256 + t;   // cell = r*B + b
    const int r    = cell >> 10;             // block-uniform
    const int b    = cell & (B_ - 1);

    if (t < K_) { s_cnt[t] = 0.f; s_val[t] = 0.f; }
    if (t == 0) s_obj = 0.f;
    __syncthreads();

    // hoisted, fully-unrolled loads -> 32 regs (static indices only)
    float v[K_];
#pragma unroll
    for (int kk = 0; kk < K_; ++kk)
        v[kk] = loss_ws[(size_t)(r * K_ + kk) * B_ + b];

    // serial top-2 scan (ascending k: lowest index wins ties)
    float m1 = v[0], m2 = 3.0e38f;
    int i1 = 0;
#pragma unroll
    for (int kk = 1; kk < K_; ++kk) {
        float x = v[kk];
        if (x < m1)      { m2 = m1; m1 = x; i1 = kk; }
        else if (x < m2) { m2 = x; }
    }

    // one-hot c row: 8 nontemporal float4 stores, 128B contiguous per lane
    {
        nfloat4* dst = (nfloat4*)(c_out + ((size_t)b * R_ + r) * K_);
#pragma unroll
        for (int q = 0; q < 8; ++q) {
            nfloat4 o = { (i1 == q * 4 + 0) ? 1.f : 0.f,
                          (i1 == q * 4 + 1) ? 1.f : 0.f,
                          (i1 == q * 4 + 2) ? 1.f : 0.f,
                          (i1 == q * 4 + 3) ? 1.f : 0.f };
            __builtin_nontemporal_store(o, dst + q);
        }
    }

    // block-local histogram (r uniform per block -> only 32 slots live)
    atomicAdd(&s_cnt[i1], 1.0f);
    atomicAdd(&s_val[i1], m2 - m1);
    atomicAdd(&s_obj, m1);
    __syncthreads();

    // block partials -> global accumulators (device-scope atomics);
    // skip zero slots to cut atomic traffic
    if (t < K_) {
        float cb = s_cnt[t];
        float vb = s_val[t];
        if (cb != 0.f) atomicAdd(&g_accum[GA_CNT + r * K_ + t], cb);
        if (vb != 0.f) atomicAdd(&g_accum[GA_VAL + r * K_ + t], vb);
    }
    if (t == 0) atomicAdd(&g_accum[GA_OBJ + r], s_obj);
    __threadfence();

    if (t == 0) {
        int prev = atomicAdd((int*)g_accum + GA_CTR, 1);
        s_last = (prev == nblocks - 1) ? 1 : 0;
    }
    __syncthreads();

    if (s_last) {
        // coherent reads of completed accumulators via atomic RMW(+0)
        float cnt = atomicAdd(&g_accum[GA_CNT + t], 0.f);
        float val = atomicAdd(&g_accum[GA_VAL + t], 0.f);
        ncm_out[t] = 0.9f * c_mean[t] + 0.1f * (cnt * (1.0f / B_));
        nv_out[t]  = 0.9f * value[t]  + 0.1f * (val * (1.0f / B_));
        if (t < R_) {
            float o = atomicAdd(&g_accum[GA_OBJ + t], 0.f);
            obj_out[t] = o * (1.0f / B_);
        }
        if (t == 0) {
            float m = 0.f;
            for (int i = 0; i < R_; ++i) m += atomicAdd(&g_accum[GA_OBJ + i], 0.f);
            obj_mean_out[0] = m * (1.0f / (B_ * R_));
        }
    }
}

// ---------------------------------------------------------------------------
extern "C" void kernel_launch(void* const* d_in, const int* in_sizes, int n_in,
                              void* d_out, int out_size, void* d_ws, size_t ws_size,
                              hipStream_t stream)
{
    const float* x      = (const float*)d_in[0];   // (B, D)
    const float* z      = (const float*)d_in[1];   // (R, K, B, L)
    const float* Us     = (const float*)d_in[2];   // (R, K, D, L)
    const float* c_mean = (const float*)d_in[3];   // (R, K)
    const float* value  = (const float*)d_in[4];   // (R, K)

    float* out          = (float*)d_out;
    float* x_out        = out;                                   // R*K*B*D
    float* c_out        = x_out + (size_t)R_ * K_ * B_ * D_;     // B*R*K
    float* obj_out      = c_out + (size_t)B_ * R_ * K_;          // R
    float* obj_mean_out = obj_out + R_;                          // 1
    float* ncm_out      = obj_mean_out + 1;                      // R*K
    float* nv_out       = ncm_out + R_ * K_;                     // R*K

    float* loss_ws = (float*)d_ws;                               // R*K*B floats, [rk][b]
    float* g_accum = loss_ws + (size_t)R_ * K_ * B_;             // 521 floats

    k1_gemm_loss<<<R_ * K_ * (B_ / BCHUNK), 256, 0, stream>>>(
        x, z, Us, x_out, loss_ws, g_accum);

    const int nblocks = 32;   // 8192 (r,b) cells / 256 threads
    k2_top2_final<<<nblocks, 256, 0, stream>>>(
        loss_ws, c_mean, value, c_out,
        obj_out, obj_mean_out, ncm_out, nv_out, g_accum, nblocks);
}

// Round 2
// 362.168 us; speedup vs baseline: 1.0604x; 1.0055x over previous
//
#include <hip/hip_runtime.h>

// Problem constants
#define R_ 8
#define K_ 32
#define B_ 1024
#define D_ 256
#define L_ 16
#define BCHUNK 128   // b-rows per block in K1

// g_accum layout (floats, in ws after loss_ws):
//   [0,256)   cnt[r*32+k]
//   [256,512) val[r*32+k]
//   [512,520) obj[r]
//   [520]     (int) arrival counter
#define GA_CNT 0
#define GA_VAL 256
#define GA_OBJ 512
#define GA_CTR 520

// native vector type for nontemporal stores (HIP float4 is a class and
// __builtin_nontemporal_store rejects it)
typedef float nfloat4 __attribute__((ext_vector_type(4)));

__device__ __forceinline__ float2 f2fma(float s, float2 u, float2 a) {
    a.x = fmaf(s, u.x, a.x);
    a.y = fmaf(s, u.y, a.y);
    return a;
}

// ---------------------------------------------------------------------------
// K1: fused x_ = z @ Us^T (per r,k) + loss[rk,b] = 0.5*sum_D (x - x_)^2
// grid: R*K*8 = 2048 blocks, 256 threads. Each lane owns 4 consecutive D
// columns (Us rows in 64 VGPRs as float2 pairs -> v_pk_fma_f32). Each wave
// does 32 b-rows, 2 at a time (hoisted loads).
//
// Loss reduction (this round): NO per-row shfl butterflies in the hot loop.
// Each lane parks its 4-column partial square-sum in LDS s_part[wave][row][lane]
// (2 conflict-free ds_write_b32 per iteration). After the loop a single
// wave-local pass reduces all 32 rows: lane pair (2l,2l+1) serially sums the
// two 32-float halves of row l (stride-65 pad -> 2-way bank alias = free),
// one shfl_xor(...,1) combines halves, even lanes emit one coalesced 128B
// loss store. Cuts DS-pipe ops 192 -> ~34 per thread and removes the
// dependent 6-step shfl chains from the inner loop.
// Block 0 additionally zero-inits the global accumulators for K2.
// ---------------------------------------------------------------------------
__global__ __launch_bounds__(256) void k1_gemm_loss(
    const float* __restrict__ x, const float* __restrict__ z,
    const float* __restrict__ Us, float* __restrict__ x_out,
    float* __restrict__ loss_ws, float* __restrict__ g_accum)
{
    __shared__ float s_part[4][32][65];   // [wave][row][lane], +1 pad

    if (blockIdx.x == 0) {
        const int t = threadIdx.x;
        g_accum[GA_CNT + t] = 0.f;
        g_accum[GA_VAL + t] = 0.f;
        if (t < R_) g_accum[GA_OBJ + t] = 0.f;
        if (t == 0) ((int*)g_accum)[GA_CTR] = 0;
    }

    const int blk   = blockIdx.x;
    const int rk    = blk >> 3;
    const int chunk = blk & 7;
    const int lane = threadIdx.x & 63;
    const int wave = threadIdx.x >> 6;

    const float* Us_rk = Us + (size_t)rk * (D_ * L_);
    const float* z_rk  = z  + (size_t)rk * (B_ * L_);
    float*       xo_rk = x_out + (size_t)rk * (B_ * D_);

    // Pack Us rows for this lane's 4 D columns into float2 pairs:
    // u01[j] = (Us[d0][j], Us[d0+1][j]),  u23[j] = (Us[d0+2][j], Us[d0+3][j])
    const int d0 = lane << 2;
    float2 u01[16], u23[16];
    {
        const float4* r0 = (const float4*)(Us_rk + (size_t)(d0 + 0) * L_);
        const float4* r1 = (const float4*)(Us_rk + (size_t)(d0 + 1) * L_);
        const float4* r2 = (const float4*)(Us_rk + (size_t)(d0 + 2) * L_);
        const float4* r3 = (const float4*)(Us_rk + (size_t)(d0 + 3) * L_);
#pragma unroll
        for (int j4 = 0; j4 < 4; ++j4) {
            float4 a = r0[j4], b = r1[j4], c = r2[j4], d = r3[j4];
            u01[j4 * 4 + 0] = make_float2(a.x, b.x);
            u01[j4 * 4 + 1] = make_float2(a.y, b.y);
            u01[j4 * 4 + 2] = make_float2(a.z, b.z);
            u01[j4 * 4 + 3] = make_float2(a.w, b.w);
            u23[j4 * 4 + 0] = make_float2(c.x, d.x);
            u23[j4 * 4 + 1] = make_float2(c.y, d.y);
            u23[j4 * 4 + 2] = make_float2(c.z, d.z);
            u23[j4 * 4 + 3] = make_float2(c.w, d.w);
        }
    }

    const int b0 = chunk * BCHUNK + wave * (BCHUNK / 4);   // 32 rows per wave
    for (int i = 0; i < BCHUNK / 4; i += 2) {
        const int ba = b0 + i;
        const int bb = b0 + i + 1;

        // ---- hoist ALL loads for both rows (max MLP) ----
        const float4* zra = (const float4*)(z_rk + (size_t)ba * L_);
        const float4* zrb = (const float4*)(z_rk + (size_t)bb * L_);
        float4 zA[4], zB[4];
#pragma unroll
        for (int j4 = 0; j4 < 4; ++j4) { zA[j4] = zra[j4]; zB[j4] = zrb[j4]; }
        float4 xa = ((const float4*)(x + (size_t)ba * D_))[lane];
        float4 xb = ((const float4*)(x + (size_t)bb * D_))[lane];

        // ---- packed-fp32 dot products ----
        float2 a01 = make_float2(0.f, 0.f), a23 = make_float2(0.f, 0.f);
        float2 b01 = make_float2(0.f, 0.f), b23 = make_float2(0.f, 0.f);
#pragma unroll
        for (int j4 = 0; j4 < 4; ++j4) {
            float4 za = zA[j4], zb = zB[j4];
            a01 = f2fma(za.x, u01[4 * j4 + 0], a01); a23 = f2fma(za.x, u23[4 * j4 + 0], a23);
            a01 = f2fma(za.y, u01[4 * j4 + 1], a01); a23 = f2fma(za.y, u23[4 * j4 + 1], a23);
            a01 = f2fma(za.z, u01[4 * j4 + 2], a01); a23 = f2fma(za.z, u23[4 * j4 + 2], a23);
            a01 = f2fma(za.w, u01[4 * j4 + 3], a01); a23 = f2fma(za.w, u23[4 * j4 + 3], a23);
            b01 = f2fma(zb.x, u01[4 * j4 + 0], b01); b23 = f2fma(zb.x, u23[4 * j4 + 0], b23);
            b01 = f2fma(zb.y, u01[4 * j4 + 1], b01); b23 = f2fma(zb.y, u23[4 * j4 + 1], b23);
            b01 = f2fma(zb.z, u01[4 * j4 + 2], b01); b23 = f2fma(zb.z, u23[4 * j4 + 2], b23);
            b01 = f2fma(zb.w, u01[4 * j4 + 3], b01); b23 = f2fma(zb.w, u23[4 * j4 + 3], b23);
        }

        // ---- streaming nontemporal stores of x_ (never re-read) ----
        nfloat4 oA = { a01.x, a01.y, a23.x, a23.y };
        nfloat4 oB = { b01.x, b01.y, b23.x, b23.y };
        __builtin_nontemporal_store(oA, (nfloat4*)(xo_rk + (size_t)ba * D_) + lane);
        __builtin_nontemporal_store(oB, (nfloat4*)(xo_rk + (size_t)bb * D_) + lane);

        // ---- per-lane 4-column partial square-sums -> LDS (no shfl) ----
        float dax = xa.x - oA.x, day = xa.y - oA.y, daz = xa.z - oA.z, daw = xa.w - oA.w;
        float dbx = xb.x - oB.x, dby = xb.y - oB.y, dbz = xb.z - oB.z, dbw = xb.w - oB.w;
        float sqA = fmaf(dax, dax, fmaf(day, day, fmaf(daz, daz, daw * daw)));
        float sqB = fmaf(dbx, dbx, fmaf(dby, dby, fmaf(dbz, dbz, dbw * dbw)));
        s_part[wave][i][lane]     = sqA;   // consecutive lanes -> consecutive banks
        s_part[wave][i + 1][lane] = sqB;
    }

    // ---- wave-local end reduction (intra-wave LDS, no barrier needed) ----
    // lane pair (2l, 2l+1) owns row l: each sums one 32-float half.
    // bank(row*65 + half*32 + j) = (row + j) % 32 -> 2 lanes/bank = free.
    {
        const int row  = lane >> 1;
        const int half = lane & 1;
        const float* p = &s_part[wave][row][half * 32];
        float s0 = 0.f, s1 = 0.f, s2 = 0.f, s3 = 0.f;
#pragma unroll
        for (int j = 0; j < 32; j += 4) {
            s0 += p[j + 0]; s1 += p[j + 1]; s2 += p[j + 2]; s3 += p[j + 3];
        }
        float s = (s0 + s1) + (s2 + s3);
        float tot = s + __shfl_xor(s, 1, 64);
        if (half == 0)   // even lanes: 32 stores, contiguous 128B segment
            loss_ws[(size_t)rk * B_ + b0 + row] = 0.5f * tot;
    }
}

// ---------------------------------------------------------------------------
// K2: per-lane serial top-2 scan, zero shuffles.
// grid = 32 blocks x 256 threads; thread t owns cell = blk*256+t = r*B + b
// (r is uniform per block since 256 | 1024). It hoists the 32 losses
// loss_ws[(r*K+k)*B + b] (coalesced 256B/wave per k, L2-resident ~1MB),
// scans min/min2/argmin in registers (lowest index wins ties, matching
// jax.lax.top_k; duplicated min => m2 == m1), writes the one-hot c row as
// 8 nontemporal float4s, then LDS-atomic histogram -> global float atomics
// -> arrival counter -> last block does the EMA/obj epilogue.
// ---------------------------------------------------------------------------
__global__ __launch_bounds__(256) void k2_top2_final(
    const float* __restrict__ loss_ws, const float* __restrict__ c_mean,
    const float* __restrict__ value, float* __restrict__ c_out,
    float* __restrict__ obj_out, float* __restrict__ obj_mean_out,
    float* __restrict__ ncm_out, float* __restrict__ nv_out,
    float* __restrict__ g_accum, int nblocks)
{
    __shared__ float s_cnt[K_];
    __shared__ float s_val[K_];
    __shared__ float s_obj;
    __shared__ int   s_last;

    const int t    = threadIdx.x;
    const int cell = blockIdx.x * 256 + t;   // cell = r*B + b
    const int r    = cell >> 10;             // block-uniform
    const int b    = cell & (B_ - 1);

    if (t < K_) { s_cnt[t] = 0.f; s_val[t] = 0.f; }
    if (t == 0) s_obj = 0.f;
    __syncthreads();

    // hoisted, fully-unrolled loads -> 32 regs (static indices only)
    float v[K_];
#pragma unroll
    for (int kk = 0; kk < K_; ++kk)
        v[kk] = loss_ws[(size_t)(r * K_ + kk) * B_ + b];

    // serial top-2 scan (ascending k: lowest index wins ties)
    float m1 = v[0], m2 = 3.0e38f;
    int i1 = 0;
#pragma unroll
    for (int kk = 1; kk < K_; ++kk) {
        float x = v[kk];
        if (x < m1)      { m2 = m1; m1 = x; i1 = kk; }
        else if (x < m2) { m2 = x; }
    }

    // one-hot c row: 8 nontemporal float4 stores, 128B contiguous per lane
    {
        nfloat4* dst = (nfloat4*)(c_out + ((size_t)b * R_ + r) * K_);
#pragma unroll
        for (int q = 0; q < 8; ++q) {
            nfloat4 o = { (i1 == q * 4 + 0) ? 1.f : 0.f,
                          (i1 == q * 4 + 1) ? 1.f : 0.f,
                          (i1 == q * 4 + 2) ? 1.f : 0.f,
                          (i1 == q * 4 + 3) ? 1.f : 0.f };
            __builtin_nontemporal_store(o, dst + q);
        }
    }

    // block-local histogram (r uniform per block -> only 32 slots live)
    atomicAdd(&s_cnt[i1], 1.0f);
    atomicAdd(&s_val[i1], m2 - m1);
    atomicAdd(&s_obj, m1);
    __syncthreads();

    // block partials -> global accumulators (device-scope atomics);
    // skip zero slots to cut atomic traffic
    if (t < K_) {
        float cb = s_cnt[t];
        float vb = s_val[t];
        if (cb != 0.f) atomicAdd(&g_accum[GA_CNT + r * K_ + t], cb);
        if (vb != 0.f) atomicAdd(&g_accum[GA_VAL + r * K_ + t], vb);
    }
    if (t == 0) atomicAdd(&g_accum[GA_OBJ + r], s_obj);
    __threadfence();

    if (t == 0) {
        int prev = atomicAdd((int*)g_accum + GA_CTR, 1);
        s_last = (prev == nblocks - 1) ? 1 : 0;
    }
    __syncthreads();

    if (s_last) {
        // coherent reads of completed accumulators via atomic RMW(+0)
        float cnt = atomicAdd(&g_accum[GA_CNT + t], 0.f);
        float val = atomicAdd(&g_accum[GA_VAL + t], 0.f);
        ncm_out[t] = 0.9f * c_mean[t] + 0.1f * (cnt * (1.0f / B_));
        nv_out[t]  = 0.9f * value[t]  + 0.1f * (val * (1.0f / B_));
        if (t < R_) {
            float o = atomicAdd(&g_accum[GA_OBJ + t], 0.f);
            obj_out[t] = o * (1.0f / B_);
        }
        if (t == 0) {
            float m = 0.f;
            for (int i = 0; i < R_; ++i) m += atomicAdd(&g_accum[GA_OBJ + i], 0.f);
            obj_mean_out[0] = m * (1.0f / (B_ * R_));
        }
    }
}

// ---------------------------------------------------------------------------
extern "C" void kernel_launch(void* const* d_in, const int* in_sizes, int n_in,
                              void* d_out, int out_size, void* d_ws, size_t ws_size,
                              hipStream_t stream)
{
    const float* x      = (const float*)d_in[0];   // (B, D)
    const float* z      = (const float*)d_in[1];   // (R, K, B, L)
    const float* Us     = (const float*)d_in[2];   // (R, K, D, L)
    const float* c_mean = (const float*)d_in[3];   // (R, K)
    const float* value  = (const float*)d_in[4];   // (R, K)

    float* out          = (float*)d_out;
    float* x_out        = out;                                   // R*K*B*D
    float* c_out        = x_out + (size_t)R_ * K_ * B_ * D_;     // B*R*K
    float* obj_out      = c_out + (size_t)B_ * R_ * K_;          // R
    float* obj_mean_out = obj_out + R_;                          // 1
    float* ncm_out      = obj_mean_out + 1;                      // R*K
    float* nv_out       = ncm_out + R_ * K_;                     // R*K

    float* loss_ws = (float*)d_ws;                               // R*K*B floats, [rk][b]
    float* g_accum = loss_ws + (size_t)R_ * K_ * B_;             // 521 floats

    k1_gemm_loss<<<R_ * K_ * (B_ / BCHUNK), 256, 0, stream>>>(
        x, z, Us, x_out, loss_ws, g_accum);

    const int nblocks = 32;   // 8192 (r,b) cells / 256 threads
    k2_top2_final<<<nblocks, 256, 0, stream>>>(
        loss_ws, c_mean, value, c_out,
        obj_out, obj_mean_out, ncm_out, nv_out, g_accum, nblocks);
}